// Round 9
// baseline (321.802 us; speedup 1.0000x reference)
//
#include <hip/hip_runtime.h>
#include <hip/hip_bf16.h>

typedef __hip_bfloat16 bf16;
typedef __attribute__((ext_vector_type(8))) short short8;   // 8 bf16 (4 VGPR)
typedef __attribute__((ext_vector_type(4))) float f32x4;    // MFMA acc

#define N_NODES 100000
#define N_EDGES 640000
#define NSB 98            // ceil(N_NODES / 1024)
#define N_TILES 6250      // N_NODES / 16

// ---------------------------------------------------------------------------
// init: zero pos[N] (hist counters); block 0 lane 0 also detects dtypes.
// flags[0]: edge_index int64 (1) / int32 (0).  flags[1]: floats f32 (1) / bf16 (0).
__global__ __launch_bounds__(256) void init_kernel(
        int4* __restrict__ pos, int n4,
        const int* __restrict__ idx, const unsigned* __restrict__ xw,
        int* __restrict__ flags) {
    int i = blockIdx.x * 256 + threadIdx.x;
    if (i < n4) pos[i] = make_int4(0, 0, 0, 0);
    if (blockIdx.x == 0 && threadIdx.x == 0) {
        int is64 = 1;
        for (int k = 1; k < 64; k += 2) is64 &= (idx[k] == 0);
        flags[0] = is64;
        int cin = 0;
        for (int k = 0; k < 128; ++k) {
            unsigned e = (xw[k] >> 7) & 0xFFu;
            cin += (e >= 0x20u && e <= 0x4Fu) ? 1 : 0;
        }
        flags[1] = (cin >= 96) ? 0 : 1;   // 1 => f32
    }
}

// ---------------------------------------------------------------------------
// CSR build: histogram -> 2-level exclusive scan -> fill (src sorted by dst).
__global__ __launch_bounds__(256) void hist_kernel(
        const int* __restrict__ eidx, int* __restrict__ deg,
        const int* __restrict__ flags, int E, int N) {
    int e0 = (blockIdx.x * 256 + threadIdx.x) * 4;
    if (e0 >= E) return;
    if (flags[0]) {
#pragma unroll
        for (int c = 0; c < 4; ++c) {
            int e = e0 + c;
            int d = eidx[2 * (E + e)];
            int s = eidx[2 * e];
            if ((unsigned)s >= (unsigned)N || (unsigned)d >= (unsigned)N) continue;
            atomicAdd(&deg[d], 1);
        }
    } else {
        int4 sv = *(const int4*)&eidx[e0];
        int4 dv = *(const int4*)&eidx[E + e0];
        const int ss[4] = {sv.x, sv.y, sv.z, sv.w};
        const int dd[4] = {dv.x, dv.y, dv.z, dv.w};
#pragma unroll
        for (int c = 0; c < 4; ++c) {
            if ((unsigned)ss[c] >= (unsigned)N || (unsigned)dd[c] >= (unsigned)N) continue;
            atomicAdd(&deg[dd[c]], 1);
        }
    }
}

__global__ __launch_bounds__(256) void scan_partial_kernel(
        const int* __restrict__ deg, int* __restrict__ off,
        int* __restrict__ bsum, int N) {
    __shared__ int ss[256];
    const int tid = threadIdx.x, blk = blockIdx.x;
    const int base = blk * 1024 + tid * 4;
    int v[4], s = 0;
#pragma unroll
    for (int c = 0; c < 4; ++c) {
        v[c] = (base + c < N) ? deg[base + c] : 0;
        s += v[c];
    }
    ss[tid] = s; __syncthreads();
    for (int o = 1; o < 256; o <<= 1) {
        int t = (tid >= o) ? ss[tid - o] : 0;
        __syncthreads();
        ss[tid] += t;
        __syncthreads();
    }
    int run = ss[tid] - s;                      // exclusive
    if (tid == 255) bsum[blk] = ss[255];
#pragma unroll
    for (int c = 0; c < 4; ++c) {
        if (base + c < N) off[base + c] = run;
        run += v[c];
    }
}

__global__ void scan_bsum_kernel(int* __restrict__ bsum, int* __restrict__ off, int N) {
    __shared__ int ss[128];
    const int tid = threadIdx.x;
    int v = (tid < NSB) ? bsum[tid] : 0;
    ss[tid] = v; __syncthreads();
    for (int o = 1; o < 128; o <<= 1) {
        int t = (tid >= o) ? ss[tid - o] : 0;
        __syncthreads();
        ss[tid] += t;
        __syncthreads();
    }
    if (tid < NSB) bsum[tid] = ss[tid] - v;     // exclusive
    if (tid == 127) off[N] = ss[127];
}

__global__ __launch_bounds__(256) void scan_add_kernel(
        int* __restrict__ off, int* __restrict__ pos,
        const int* __restrict__ bsum, int N) {
    const int blk = blockIdx.x, tid = threadIdx.x;
    const int add = bsum[blk];
    const int base = blk * 1024 + tid * 4;
#pragma unroll
    for (int c = 0; c < 4; ++c) {
        int i = base + c;
        if (i < N) { int t = off[i] + add; off[i] = t; pos[i] = t; }
    }
}

__global__ __launch_bounds__(256) void fill_kernel(
        const int* __restrict__ eidx, int* __restrict__ pos,
        int* __restrict__ srcs, const int* __restrict__ flags, int E, int N) {
    int e0 = (blockIdx.x * 256 + threadIdx.x) * 4;
    if (e0 >= E) return;
    int ss[4], dd[4];
    if (flags[0]) {
#pragma unroll
        for (int c = 0; c < 4; ++c) { ss[c] = eidx[2 * (e0 + c)]; dd[c] = eidx[2 * (E + e0 + c)]; }
    } else {
        int4 sv = *(const int4*)&eidx[e0];
        int4 dv = *(const int4*)&eidx[E + e0];
        ss[0] = sv.x; ss[1] = sv.y; ss[2] = sv.z; ss[3] = sv.w;
        dd[0] = dv.x; dd[1] = dv.y; dd[2] = dv.z; dd[3] = dv.w;
    }
#pragma unroll
    for (int c = 0; c < 4; ++c) {
        if ((unsigned)ss[c] >= (unsigned)N || (unsigned)dd[c] >= (unsigned)N) continue;
        int p = atomicAdd(&pos[dd[c]], 1);
        srcs[p] = ss[c];
    }
}

// ---------------------------------------------------------------------------
// Gather-reduce 1: one wave per dst node, lane = dim (64). Batched 8-deep
// with uniform predication (cdeg is wave-uniform).
__global__ __launch_bounds__(256) void gather1_kernel(
        const int* __restrict__ srcs, const int* __restrict__ off,
        const bf16* __restrict__ xl, bf16* __restrict__ agg, int N) {
    const int node = blockIdx.x * 4 + (threadIdx.x >> 6);
    const int lane = threadIdx.x & 63;
    if (node >= N) return;
    const int a = off[node], b = off[node + 1];
    float acc = 0.f;
    for (int base = a; base < b; base += 64) {
        const int cdeg = min(b - base, 64);
        int sv = (lane < cdeg) ? srcs[base + lane] : 0;
        for (int bb = 0; bb < cdeg; bb += 8) {
            float v[8];
#pragma unroll
            for (int t = 0; t < 8; ++t) {
                int idx = bb + t;
                int s = __shfl(sv, idx < cdeg ? idx : 0);
                float val = (float)xl[(size_t)s * 64 + lane];
                v[t] = (idx < cdeg) ? val : 0.f;
            }
            acc += ((v[0] + v[1]) + (v[2] + v[3])) + ((v[4] + v[5]) + (v[6] + v[7]));
        }
    }
    agg[(size_t)node * 64 + lane] = __float2bfloat16(acc);
}

// Gather-reduce 2: one wave per node; halves take even/odd edges, 32 dims.
__global__ __launch_bounds__(256) void gather2_kernel(
        const int* __restrict__ srcs, const int* __restrict__ off,
        const bf16* __restrict__ hl, bf16* __restrict__ agg, int N) {
    const int node = blockIdx.x * 4 + (threadIdx.x >> 6);
    const int lane = threadIdx.x & 63;
    if (node >= N) return;
    const int j = lane & 31, half = lane >> 5;
    const int a = off[node], b = off[node + 1];
    float acc = 0.f;
    for (int base = a; base < b; base += 64) {
        const int cdeg = min(b - base, 64);
        int sv = (lane < cdeg) ? srcs[base + lane] : 0;
        for (int bb = 0; bb < cdeg; bb += 8) {
            float v[4];
#pragma unroll
            for (int t = 0; t < 4; ++t) {
                int idx = bb + half + 2 * t;
                int s = __shfl(sv, idx < cdeg ? idx : 0);
                float val = (float)hl[(size_t)s * 32 + j];
                v[t] = (idx < cdeg) ? val : 0.f;
            }
            acc += (v[0] + v[1]) + (v[2] + v[3]);
        }
    }
    acc += __shfl_down(acc, 32);
    if (half == 0) agg[(size_t)node * 32 + j] = __float2bfloat16(acc);
}

// ===========================================================================
// MFMA fragment helpers (16x16x32 bf16):
//   A[m][k]: m = lane&15, k = quad*8 + j   (16B contiguous per lane)
//   B[k][n]: n = lane&15, k = quad*8 + j
//   C/D:     col = lane&15, row = quad*4 + reg
// ===========================================================================
__device__ __forceinline__ short8 load_frag(const void* base, size_t eoff, int f32) {
    if (f32) {
        const float* p = (const float*)base + eoff;
        short8 r;
#pragma unroll
        for (int j = 0; j < 8; ++j) {
            union { bf16 b; short s; } u;
            u.b = __float2bfloat16(p[j]);
            r[j] = u.s;
        }
        return r;
    }
    return *(const short8*)((const short*)base + eoff);
}

// lin1: xl[N,64] = x@W1l^T, xr[N,64] = x@W1r^T — one pass over x.
__global__ __launch_bounds__(256) void lin1_kernel(
        const void* __restrict__ x, const void* __restrict__ W1l,
        const void* __restrict__ W1r, bf16* __restrict__ xl,
        bf16* __restrict__ xr, const int* __restrict__ flags) {
    const int f32 = flags[1];
    const int tile = blockIdx.x * 4 + (threadIdx.x >> 6);
    if (tile >= N_TILES) return;
    const int lane = threadIdx.x & 63;
    const int row0 = tile * 16;
    const int m = lane & 15, quad = lane >> 4;

    f32x4 acc[8];
#pragma unroll
    for (int nt = 0; nt < 8; ++nt) acc[nt] = (f32x4){0.f, 0.f, 0.f, 0.f};

    const size_t arow = (size_t)(row0 + m) * 128;
    short8 a[4];
#pragma unroll
    for (int ks = 0; ks < 4; ++ks)
        a[ks] = load_frag(x, arow + ks * 32 + quad * 8, f32);

#pragma unroll
    for (int ks = 0; ks < 4; ++ks) {
#pragma unroll
        for (int nt = 0; nt < 8; ++nt) {
            const void* Wb = (nt < 4) ? W1l : W1r;
            short8 bfr = load_frag(Wb, (size_t)((nt & 3) * 16 + m) * 128 + ks * 32 + quad * 8, f32);
            acc[nt] = __builtin_amdgcn_mfma_f32_16x16x32_bf16(a[ks], bfr, acc[nt], 0, 0, 0);
        }
    }

#pragma unroll
    for (int reg = 0; reg < 4; ++reg) {
        const int row = row0 + quad * 4 + reg;
#pragma unroll
        for (int nt = 0; nt < 8; ++nt) {
            const int col = (nt & 3) * 16 + m;
            bf16* dst = (nt < 4) ? xl : xr;
            dst[(size_t)row * 64 + col] = __float2bfloat16(acc[nt][reg]);
        }
    }
}

// Fused combine1 + lin2: h = relu(agg/deg + b1 + xr) built directly in
// A-layout registers (lane (m,quad) owns row m, cols ks*32+quad*8..+7),
// then hl = h@W2l^T, hr = h@W2r^T. h is never materialized.
__global__ __launch_bounds__(256) void cl2_kernel(
        const bf16* __restrict__ agg, const bf16* __restrict__ xr,
        const int* __restrict__ off, const void* __restrict__ b1,
        const void* __restrict__ W2l, const void* __restrict__ W2r,
        bf16* __restrict__ hl, bf16* __restrict__ hr,
        const int* __restrict__ flags) {
    const int f32 = flags[1];
    const int tile = blockIdx.x * 4 + (threadIdx.x >> 6);
    if (tile >= N_TILES) return;
    const int lane = threadIdx.x & 63;
    const int row0 = tile * 16;
    const int m = lane & 15, quad = lane >> 4;
    const int row = row0 + m;

    const float inv = 1.0f / fmaxf((float)(off[row + 1] - off[row]), 1.0f);

    short8 a[2];
#pragma unroll
    for (int ks = 0; ks < 2; ++ks) {
        const size_t co = (size_t)row * 64 + ks * 32 + quad * 8;
        short8 ag = *(const short8*)((const short*)agg + co);
        short8 xv = *(const short8*)((const short*)xr + co);
        short8 bv = load_frag(b1, ks * 32 + quad * 8, f32);
#pragma unroll
        for (int j = 0; j < 8; ++j) {
            union { short s; bf16 b; } ua, ux, ub, uo;
            ua.s = ag[j]; ux.s = xv[j]; ub.s = bv[j];
            float v = (float)ua.b * inv + (float)ub.b + (float)ux.b;
            uo.b = __float2bfloat16(fmaxf(v, 0.0f));
            a[ks][j] = uo.s;
        }
    }

    f32x4 acc[4];
#pragma unroll
    for (int nt = 0; nt < 4; ++nt) acc[nt] = (f32x4){0.f, 0.f, 0.f, 0.f};

#pragma unroll
    for (int ks = 0; ks < 2; ++ks) {
#pragma unroll
        for (int nt = 0; nt < 4; ++nt) {
            const void* Wb = (nt < 2) ? W2l : W2r;
            short8 bfr = load_frag(Wb, (size_t)((nt & 1) * 16 + m) * 64 + ks * 32 + quad * 8, f32);
            acc[nt] = __builtin_amdgcn_mfma_f32_16x16x32_bf16(a[ks], bfr, acc[nt], 0, 0, 0);
        }
    }

#pragma unroll
    for (int reg = 0; reg < 4; ++reg) {
        const int orow = row0 + quad * 4 + reg;
#pragma unroll
        for (int nt = 0; nt < 4; ++nt) {
            const int col = (nt & 1) * 16 + m;
            bf16* dst = (nt < 2) ? hl : hr;
            dst[(size_t)orow * 32 + col] = __float2bfloat16(acc[nt][reg]);
        }
    }
}

// Final elementwise: out = agg2/deg + b2 + hr.  4 cols/thread.
__global__ __launch_bounds__(256) void final_kernel(
        const bf16* __restrict__ agg, const bf16* __restrict__ hr,
        const int* __restrict__ off, const void* __restrict__ b2,
        void* __restrict__ out, const int* __restrict__ flags, int N) {
    const int f32 = flags[1];
    int tid = blockIdx.x * 256 + threadIdx.x;
    int row = tid >> 3, c4 = (tid & 7) * 4;
    if (row >= N) return;
    const float inv = 1.0f / fmaxf((float)(off[row + 1] - off[row]), 1.0f);
    union { ushort4 u; bf16 b[4]; } av, hv;
    av.u = *(const ushort4*)&agg[(size_t)row * 32 + c4];
    hv.u = *(const ushort4*)&hr[(size_t)row * 32 + c4];
    float v[4];
#pragma unroll
    for (int c = 0; c < 4; ++c) {
        float bb = f32 ? ((const float*)b2)[c4 + c] : (float)((const bf16*)b2)[c4 + c];
        v[c] = (float)av.b[c] * inv + bb + (float)hv.b[c];
    }
    if (f32) {
        *(float4*)&((float*)out)[(size_t)row * 32 + c4] = make_float4(v[0], v[1], v[2], v[3]);
    } else {
        union { ushort4 u; bf16 b[4]; } pk;
#pragma unroll
        for (int c = 0; c < 4; ++c) pk.b[c] = __float2bfloat16(v[c]);
        *(ushort4*)&((bf16*)out)[(size_t)row * 32 + c4] = pk.u;
    }
}

// ---------------------------------------------------------------------------
extern "C" void kernel_launch(void* const* d_in, const int* in_sizes, int n_in,
                              void* d_out, int out_size, void* d_ws, size_t ws_size,
                              hipStream_t stream) {
    const void* x   = d_in[0];
    const int*  eix = (const int*)d_in[1];
    const void* W1l = d_in[2];
    const void* b1  = d_in[3];
    const void* W1r = d_in[4];
    const void* W2l = d_in[5];
    const void* b2  = d_in[6];
    const void* W2r = d_in[7];

    const int N = N_NODES;
    const int E = N_EDGES;

    // Workspace layout (~56 MB; ws_size measured at 256 MiB via harness poison):
    //   flags int[2]       @ 0
    //   agg   bf16[N*64]   @ 256     (gather1 out; reused bf16[N*32] by gather2)
    //   xl    bf16[N*64]   @ 256 + N*128
    //   xr    bf16[N*64]   @ 256 + N*256
    //   hl    bf16[N*32]   @ 256 + N*384
    //   hr    bf16[N*32]   @ 256 + N*448
    //   off   int[N+4]     @ 256 + N*512
    //   pos   int[N]       @ off + (N+4)*4
    //   srcs  int[E]       @ pos + N*4
    //   bsum  int[NSB]     @ srcs + E*4
    char* ws = (char*)d_ws;
    int*   flags = (int*)ws;
    bf16*  agg   = (bf16*)(ws + 256);
    bf16*  xl    = (bf16*)(ws + 256 + (size_t)N * 128);
    bf16*  xr    = (bf16*)(ws + 256 + (size_t)N * 256);
    bf16*  hl    = (bf16*)(ws + 256 + (size_t)N * 384);
    bf16*  hr    = (bf16*)(ws + 256 + (size_t)N * 448);
    int*   off   = (int*) (ws + 256 + (size_t)N * 512);
    int*   pos   = off + (N + 4);
    int*   srcs  = pos + N;
    int*   bsum  = srcs + E;

    // init: zero pos + detect flags
    init_kernel<<<(N / 4 + 255) / 256, 256, 0, stream>>>(
        (int4*)pos, N / 4, eix, (const unsigned*)x, flags);

    // --- CSR build ---
    hist_kernel<<<E / 1024, 256, 0, stream>>>(eix, pos, flags, E, N);
    scan_partial_kernel<<<NSB, 256, 0, stream>>>(pos, off, bsum, N);
    scan_bsum_kernel<<<1, 128, 0, stream>>>(bsum, off, N);
    scan_add_kernel<<<NSB, 256, 0, stream>>>(off, pos, bsum, N);
    fill_kernel<<<E / 1024, 256, 0, stream>>>(eix, pos, srcs, flags, E, N);

    const int gt = (N_TILES + 3) / 4;   // 1563

    // xl = x@W1l^T, xr = x@W1r^T (one x pass)
    lin1_kernel<<<gt, 256, 0, stream>>>(x, W1l, W1r, xl, xr, flags);

    // agg[d] = sum xl[src]
    gather1_kernel<<<(N + 3) / 4, 256, 0, stream>>>(srcs, off, xl, agg, N);

    // h = relu(agg/deg + b1 + xr) in-register; hl = h@W2l^T, hr = h@W2r^T
    cl2_kernel<<<gt, 256, 0, stream>>>(agg, xr, off, b1, W2l, W2r, hl, hr, flags);

    // agg2[d] = sum hl[src]
    gather2_kernel<<<(N + 3) / 4, 256, 0, stream>>>(srcs, off, hl, agg, N);

    // out = agg2/deg + b2 + hr
    final_kernel<<<(N * 32 / 4 + 255) / 256, 256, 0, stream>>>(
        agg, hr, off, b2, d_out, flags, N);
}

// Round 10
// 290.534 us; speedup vs baseline: 1.1076x; 1.1076x over previous
//
#include <hip/hip_runtime.h>
#include <hip/hip_bf16.h>

typedef __hip_bfloat16 bf16;
typedef __attribute__((ext_vector_type(8))) short short8;   // 8 bf16 (4 VGPR)
typedef __attribute__((ext_vector_type(4))) float f32x4;    // MFMA acc

#define N_NODES 100000
#define N_EDGES 640000
#define NSB 98            // ceil(N_NODES / 1024)
#define N_TILES 6250      // N_NODES / 16

// ---------------------------------------------------------------------------
// init: zero pos[N] (hist counters); block 0 lane 0 also detects dtypes.
// flags[0]: edge_index int64 (1) / int32 (0).  flags[1]: floats f32 (1) / bf16 (0).
__global__ __launch_bounds__(256) void init_kernel(
        int4* __restrict__ pos, int n4,
        const int* __restrict__ idx, const unsigned* __restrict__ xw,
        int* __restrict__ flags) {
    int i = blockIdx.x * 256 + threadIdx.x;
    if (i < n4) pos[i] = make_int4(0, 0, 0, 0);
    if (blockIdx.x == 0 && threadIdx.x == 0) {
        int is64 = 1;
        for (int k = 1; k < 64; k += 2) is64 &= (idx[k] == 0);
        flags[0] = is64;
        int cin = 0;
        for (int k = 0; k < 128; ++k) {
            unsigned e = (xw[k] >> 7) & 0xFFu;
            cin += (e >= 0x20u && e <= 0x4Fu) ? 1 : 0;
        }
        flags[1] = (cin >= 96) ? 0 : 1;   // 1 => f32
    }
}

// ---------------------------------------------------------------------------
// CSR build: histogram -> 2-level exclusive scan -> fill (src sorted by dst).
__global__ __launch_bounds__(256) void hist_kernel(
        const int* __restrict__ eidx, int* __restrict__ deg,
        const int* __restrict__ flags, int E, int N) {
    int e0 = (blockIdx.x * 256 + threadIdx.x) * 4;
    if (e0 >= E) return;
    if (flags[0]) {
#pragma unroll
        for (int c = 0; c < 4; ++c) {
            int e = e0 + c;
            int d = eidx[2 * (E + e)];
            int s = eidx[2 * e];
            if ((unsigned)s >= (unsigned)N || (unsigned)d >= (unsigned)N) continue;
            atomicAdd(&deg[d], 1);
        }
    } else {
        int4 sv = *(const int4*)&eidx[e0];
        int4 dv = *(const int4*)&eidx[E + e0];
        const int ss[4] = {sv.x, sv.y, sv.z, sv.w};
        const int dd[4] = {dv.x, dv.y, dv.z, dv.w};
#pragma unroll
        for (int c = 0; c < 4; ++c) {
            if ((unsigned)ss[c] >= (unsigned)N || (unsigned)dd[c] >= (unsigned)N) continue;
            atomicAdd(&deg[dd[c]], 1);
        }
    }
}

__global__ __launch_bounds__(256) void scan_partial_kernel(
        const int* __restrict__ deg, int* __restrict__ off,
        int* __restrict__ bsum, int N) {
    __shared__ int ss[256];
    const int tid = threadIdx.x, blk = blockIdx.x;
    const int base = blk * 1024 + tid * 4;
    int v[4], s = 0;
#pragma unroll
    for (int c = 0; c < 4; ++c) {
        v[c] = (base + c < N) ? deg[base + c] : 0;
        s += v[c];
    }
    ss[tid] = s; __syncthreads();
    for (int o = 1; o < 256; o <<= 1) {
        int t = (tid >= o) ? ss[tid - o] : 0;
        __syncthreads();
        ss[tid] += t;
        __syncthreads();
    }
    int run = ss[tid] - s;                      // exclusive
    if (tid == 255) bsum[blk] = ss[255];
#pragma unroll
    for (int c = 0; c < 4; ++c) {
        if (base + c < N) off[base + c] = run;
        run += v[c];
    }
}

__global__ void scan_bsum_kernel(int* __restrict__ bsum, int* __restrict__ off, int N) {
    __shared__ int ss[128];
    const int tid = threadIdx.x;
    int v = (tid < NSB) ? bsum[tid] : 0;
    ss[tid] = v; __syncthreads();
    for (int o = 1; o < 128; o <<= 1) {
        int t = (tid >= o) ? ss[tid - o] : 0;
        __syncthreads();
        ss[tid] += t;
        __syncthreads();
    }
    if (tid < NSB) bsum[tid] = ss[tid] - v;     // exclusive
    if (tid == 127) off[N] = ss[127];
}

__global__ __launch_bounds__(256) void scan_add_kernel(
        int* __restrict__ off, int* __restrict__ pos,
        const int* __restrict__ bsum, int N) {
    const int blk = blockIdx.x, tid = threadIdx.x;
    const int add = bsum[blk];
    const int base = blk * 1024 + tid * 4;
#pragma unroll
    for (int c = 0; c < 4; ++c) {
        int i = base + c;
        if (i < N) { int t = off[i] + add; off[i] = t; pos[i] = t; }
    }
}

__global__ __launch_bounds__(256) void fill_kernel(
        const int* __restrict__ eidx, int* __restrict__ pos,
        int* __restrict__ srcs, const int* __restrict__ flags, int E, int N) {
    int e0 = (blockIdx.x * 256 + threadIdx.x) * 4;
    if (e0 >= E) return;
    int ss[4], dd[4];
    if (flags[0]) {
#pragma unroll
        for (int c = 0; c < 4; ++c) { ss[c] = eidx[2 * (e0 + c)]; dd[c] = eidx[2 * (E + e0 + c)]; }
    } else {
        int4 sv = *(const int4*)&eidx[e0];
        int4 dv = *(const int4*)&eidx[E + e0];
        ss[0] = sv.x; ss[1] = sv.y; ss[2] = sv.z; ss[3] = sv.w;
        dd[0] = dv.x; dd[1] = dv.y; dd[2] = dv.z; dd[3] = dv.w;
    }
#pragma unroll
    for (int c = 0; c < 4; ++c) {
        if ((unsigned)ss[c] >= (unsigned)N || (unsigned)dd[c] >= (unsigned)N) continue;
        int p = atomicAdd(&pos[dd[c]], 1);
        srcs[p] = ss[c];
    }
}

// ---------------------------------------------------------------------------
// Gather-reduce 1 + fused combine epilogue. One wave per node, lane = dim.
// h = relu(sum(xl[src])/deg + b1 + xr)   (f32 accumulate, one rounding)
__global__ __launch_bounds__(256) void gather1_kernel(
        const int* __restrict__ srcs, const int* __restrict__ off,
        const bf16* __restrict__ xl, const bf16* __restrict__ xr,
        const void* __restrict__ b1, bf16* __restrict__ h,
        const int* __restrict__ flags, int N) {
    const int node = blockIdx.x * 4 + (threadIdx.x >> 6);
    const int lane = threadIdx.x & 63;
    if (node >= N) return;
    const int a = off[node], b = off[node + 1];
    float acc = 0.f;
    for (int base = a; base < b; base += 64) {
        const int cdeg = min(b - base, 64);
        int sv = (lane < cdeg) ? srcs[base + lane] : 0;
        for (int bb = 0; bb < cdeg; bb += 8) {
            float v[8];
#pragma unroll
            for (int t = 0; t < 8; ++t) {
                int idx = bb + t;
                int s = __shfl(sv, idx < cdeg ? idx : 0);
                float val = (float)xl[(size_t)s * 64 + lane];
                v[t] = (idx < cdeg) ? val : 0.f;
            }
            acc += ((v[0] + v[1]) + (v[2] + v[3])) + ((v[4] + v[5]) + (v[6] + v[7]));
        }
    }
    const int f32 = flags[1];
    const float bb = f32 ? ((const float*)b1)[lane] : (float)((const bf16*)b1)[lane];
    const float inv = 1.0f / fmaxf((float)(b - a), 1.0f);
    float v = acc * inv + bb + (float)xr[(size_t)node * 64 + lane];
    h[(size_t)node * 64 + lane] = __float2bfloat16(fmaxf(v, 0.0f));
}

// Gather-reduce 2 + fused final epilogue. Halves take even/odd edges, 32 dims.
// out = sum(hl[src])/deg + b2 + hr
__global__ __launch_bounds__(256) void gather2_kernel(
        const int* __restrict__ srcs, const int* __restrict__ off,
        const bf16* __restrict__ hl, const bf16* __restrict__ hr,
        const void* __restrict__ b2, void* __restrict__ out,
        const int* __restrict__ flags, int N) {
    const int node = blockIdx.x * 4 + (threadIdx.x >> 6);
    const int lane = threadIdx.x & 63;
    if (node >= N) return;
    const int j = lane & 31, half = lane >> 5;
    const int a = off[node], b = off[node + 1];
    float acc = 0.f;
    for (int base = a; base < b; base += 64) {
        const int cdeg = min(b - base, 64);
        int sv = (lane < cdeg) ? srcs[base + lane] : 0;
        for (int bb = 0; bb < cdeg; bb += 8) {
            float v[4];
#pragma unroll
            for (int t = 0; t < 4; ++t) {
                int idx = bb + half + 2 * t;
                int s = __shfl(sv, idx < cdeg ? idx : 0);
                float val = (float)hl[(size_t)s * 32 + j];
                v[t] = (idx < cdeg) ? val : 0.f;
            }
            acc += (v[0] + v[1]) + (v[2] + v[3]);
        }
    }
    acc += __shfl_down(acc, 32);
    if (half == 0) {
        const int f32 = flags[1];
        const float bb = f32 ? ((const float*)b2)[j] : (float)((const bf16*)b2)[j];
        const float inv = 1.0f / fmaxf((float)(b - a), 1.0f);
        float v = acc * inv + bb + (float)hr[(size_t)node * 32 + j];
        if (f32) ((float*)out)[(size_t)node * 32 + j] = v;
        else     ((bf16*)out)[(size_t)node * 32 + j] = __float2bfloat16(v);
    }
}

// ===========================================================================
// MFMA fragment helpers (16x16x32 bf16):
//   A[m][k]: m = lane&15, k = quad*8 + j   (16B contiguous per lane)
//   B[k][n]: n = lane&15, k = quad*8 + j
//   C/D:     col = lane&15, row = quad*4 + reg
// ===========================================================================
__device__ __forceinline__ short8 load_frag(const void* base, size_t eoff, int f32) {
    if (f32) {
        const float* p = (const float*)base + eoff;
        short8 r;
#pragma unroll
        for (int j = 0; j < 8; ++j) {
            union { bf16 b; short s; } u;
            u.b = __float2bfloat16(p[j]);
            r[j] = u.s;
        }
        return r;
    }
    return *(const short8*)((const short*)base + eoff);
}

// Layer-1 GEMM: y[N,64] = x[N,128] @ W^T.  Stationary-B (16 frags = 64 VGPR),
// grid-stride over 16-row tiles.  [Round-8 proven pattern: <41 us]
__global__ __launch_bounds__(256) void lin1_kernel(
        const void* __restrict__ x, const void* __restrict__ W,
        bf16* __restrict__ y, const int* __restrict__ flags) {
    const int f32 = flags[1];
    const int nwaves = gridDim.x * 4;
    const int wid = blockIdx.x * 4 + (threadIdx.x >> 6);
    const int lane = threadIdx.x & 63;
    const int m = lane & 15, quad = lane >> 4;

    short8 bfr[16];
#pragma unroll
    for (int ks = 0; ks < 4; ++ks)
#pragma unroll
        for (int nt = 0; nt < 4; ++nt)
            bfr[ks * 4 + nt] =
                load_frag(W, (size_t)(nt * 16 + m) * 128 + ks * 32 + quad * 8, f32);

    for (int tile = wid; tile < N_TILES; tile += nwaves) {
        const int row0 = tile * 16;
        f32x4 acc[4];
#pragma unroll
        for (int nt = 0; nt < 4; ++nt) acc[nt] = (f32x4){0.f, 0.f, 0.f, 0.f};

        const size_t arow = (size_t)(row0 + m) * 128;
        short8 a[4];
#pragma unroll
        for (int ks = 0; ks < 4; ++ks)
            a[ks] = load_frag(x, arow + ks * 32 + quad * 8, f32);
#pragma unroll
        for (int ks = 0; ks < 4; ++ks)
#pragma unroll
            for (int nt = 0; nt < 4; ++nt)
                acc[nt] = __builtin_amdgcn_mfma_f32_16x16x32_bf16(
                    a[ks], bfr[ks * 4 + nt], acc[nt], 0, 0, 0);

#pragma unroll
        for (int reg = 0; reg < 4; ++reg) {
            const int row = row0 + quad * 4 + reg;
#pragma unroll
            for (int nt = 0; nt < 4; ++nt)
                y[(size_t)row * 64 + nt * 16 + m] = __float2bfloat16(acc[nt][reg]);
        }
    }
}

// Layer-2 dual GEMM: hl = h@W2l^T, hr = h@W2r^T.  Stationary-B (8 frags =
// 32 VGPR), grid-stride.  h always bf16 (ws).
__global__ __launch_bounds__(256) void lin2_kernel(
        const bf16* __restrict__ h, const void* __restrict__ W2l,
        const void* __restrict__ W2r, bf16* __restrict__ hl,
        bf16* __restrict__ hr, const int* __restrict__ flags) {
    const int f32 = flags[1];
    const int nwaves = gridDim.x * 4;
    const int wid = blockIdx.x * 4 + (threadIdx.x >> 6);
    const int lane = threadIdx.x & 63;
    const int m = lane & 15, quad = lane >> 4;

    short8 bfr[8];
#pragma unroll
    for (int ks = 0; ks < 2; ++ks)
#pragma unroll
        for (int nt = 0; nt < 4; ++nt) {
            const void* Wb = (nt < 2) ? W2l : W2r;
            bfr[ks * 4 + nt] =
                load_frag(Wb, (size_t)((nt & 1) * 16 + m) * 64 + ks * 32 + quad * 8, f32);
        }

    for (int tile = wid; tile < N_TILES; tile += nwaves) {
        const int row0 = tile * 16;
        f32x4 acc[4];
#pragma unroll
        for (int nt = 0; nt < 4; ++nt) acc[nt] = (f32x4){0.f, 0.f, 0.f, 0.f};

        const size_t arow = (size_t)(row0 + m) * 64;
        short8 a[2];
#pragma unroll
        for (int ks = 0; ks < 2; ++ks)
            a[ks] = *(const short8*)((const short*)h + arow + ks * 32 + quad * 8);
#pragma unroll
        for (int ks = 0; ks < 2; ++ks)
#pragma unroll
            for (int nt = 0; nt < 4; ++nt)
                acc[nt] = __builtin_amdgcn_mfma_f32_16x16x32_bf16(
                    a[ks], bfr[ks * 4 + nt], acc[nt], 0, 0, 0);

#pragma unroll
        for (int reg = 0; reg < 4; ++reg) {
            const int row = row0 + quad * 4 + reg;
#pragma unroll
            for (int nt = 0; nt < 4; ++nt) {
                bf16* dst = (nt < 2) ? hl : hr;
                dst[(size_t)row * 32 + (nt & 1) * 16 + m] = __float2bfloat16(acc[nt][reg]);
            }
        }
    }
}

// ---------------------------------------------------------------------------
extern "C" void kernel_launch(void* const* d_in, const int* in_sizes, int n_in,
                              void* d_out, int out_size, void* d_ws, size_t ws_size,
                              hipStream_t stream) {
    const void* x   = d_in[0];
    const int*  eix = (const int*)d_in[1];
    const void* W1l = d_in[2];
    const void* b1  = d_in[3];
    const void* W1r = d_in[4];
    const void* W2l = d_in[5];
    const void* b2  = d_in[6];
    const void* W2r = d_in[7];

    const int N = N_NODES;
    const int E = N_EDGES;

    // Workspace layout (~55 MB of 256 MiB):
    //   flags int[2]       @ 0
    //   xl    bf16[N*64]   @ 256
    //   xr    bf16[N*64]   @ 256 + N*128
    //   h     bf16[N*64]   @ 256 + N*256
    //   hl    bf16[N*32]   @ 256 + N*384
    //   hr    bf16[N*32]   @ 256 + N*448
    //   off   int[N+4]     @ 256 + N*512
    //   pos   int[N]       @ off + (N+4)*4
    //   srcs  int[E]       @ pos + N*4
    //   bsum  int[NSB]     @ srcs + E*4
    char* ws = (char*)d_ws;
    int*   flags = (int*)ws;
    bf16*  xl    = (bf16*)(ws + 256);
    bf16*  xr    = (bf16*)(ws + 256 + (size_t)N * 128);
    bf16*  h     = (bf16*)(ws + 256 + (size_t)N * 256);
    bf16*  hl    = (bf16*)(ws + 256 + (size_t)N * 384);
    bf16*  hr    = (bf16*)(ws + 256 + (size_t)N * 448);
    int*   off   = (int*) (ws + 256 + (size_t)N * 512);
    int*   pos   = off + (N + 4);
    int*   srcs  = pos + N;
    int*   bsum  = srcs + E;

    // init: zero pos + detect flags
    init_kernel<<<(N / 4 + 255) / 256, 256, 0, stream>>>(
        (int4*)pos, N / 4, eix, (const unsigned*)x, flags);

    // --- CSR build ---
    hist_kernel<<<E / 1024, 256, 0, stream>>>(eix, pos, flags, E, N);
    scan_partial_kernel<<<NSB, 256, 0, stream>>>(pos, off, bsum, N);
    scan_bsum_kernel<<<1, 128, 0, stream>>>(bsum, off, N);
    scan_add_kernel<<<NSB, 256, 0, stream>>>(off, pos, bsum, N);
    fill_kernel<<<E / 1024, 256, 0, stream>>>(eix, pos, srcs, flags, E, N);

    const int gg = 782;   // 3128 waves grid-striding 6250 tiles

    // xl = x@W1l^T, xr = x@W1r^T  (stationary-B MFMA, proven pattern)
    lin1_kernel<<<gg, 256, 0, stream>>>(x, W1l, xl, flags);
    lin1_kernel<<<gg, 256, 0, stream>>>(x, W1r, xr, flags);

    // h = relu(sum(xl[src])/deg + b1 + xr)   (gather + fused combine)
    gather1_kernel<<<(N + 3) / 4, 256, 0, stream>>>(srcs, off, xl, xr, b1, h, flags, N);

    // hl = h@W2l^T, hr = h@W2r^T
    lin2_kernel<<<gg, 256, 0, stream>>>(h, W2l, W2r, hl, hr, flags);

    // out = sum(hl[src])/deg + b2 + hr   (gather + fused final)
    gather2_kernel<<<(N + 3) / 4, 256, 0, stream>>>(srcs, off, hl, hr, b2, d_out, flags, N);
}